// Round 4
// baseline (714.050 us; speedup 1.0000x reference)
//
#include <hip/hip_runtime.h>

#define NEG_VAL -1000000000.0f
#define MAXDEG  192      // padded CSR row capacity (deg ~ Poisson(32); P(>192) ~ 0)
#define SEGF    1024     // floats per fill segment (one block each); N % 1024 == 0

// ---------------- fallback path (proven R3 kernels) ----------------

__global__ __launch_bounds__(256) void fill_and_dots(
    float4* __restrict__ out4, long long n4, int fillBlocks,
    const float* __restrict__ h, const float* __restrict__ W,
    float* __restrict__ a, float* __restrict__ c, int N)
{
    if ((int)blockIdx.x < fillBlocks) {
        long long i = (long long)blockIdx.x * 256 + threadIdx.x;
        if (i < n4) out4[i] = make_float4(NEG_VAL, NEG_VAL, NEG_VAL, NEG_VAL);
    } else {
        int gid  = (blockIdx.x - fillBlocks) * 256 + threadIdx.x;
        int node = gid >> 6;
        int lane = threadIdx.x & 63;
        if (node >= N) return;
        const float2* h2 = (const float2*)(h + (size_t)node * 128);
        float2 v  = h2[lane];
        float2 wd = ((const float2*)W)[lane];
        float2 ws = ((const float2*)(W + 128))[lane];
        float sd = v.x * wd.x + v.y * wd.y;
        float ss = v.x * ws.x + v.y * ws.y;
        #pragma unroll
        for (int off = 32; off; off >>= 1) {
            sd += __shfl_xor(sd, off, 64);
            ss += __shfl_xor(ss, off, 64);
        }
        if (lane == 0) { a[node] = sd; c[node] = ss; }
    }
}

__global__ __launch_bounds__(256) void edge_scatter(
    const int* __restrict__ src, const int* __restrict__ dst,
    const float* __restrict__ wgt, const float* __restrict__ a,
    const float* __restrict__ c, const float* __restrict__ W,
    const float* __restrict__ b, float* __restrict__ out, int E, int N)
{
    int e = blockIdx.x * blockDim.x + threadIdx.x;
    if (e >= E) return;
    int s = src[e];
    int d = dst[e];
    out[(size_t)d * N + s] = fmaf(wgt[e], W[256], a[d] + c[s] + b[0]);
}

// ---------------- CSR fused path ----------------

__global__ __launch_bounds__(256) void zero_cursor(int* __restrict__ cursor, int N) {
    int i = blockIdx.x * 256 + threadIdx.x;
    if (i < N) cursor[i] = 0;
}

// blocks [0, dotBlocks): per-node dots (wave per node)
// blocks [dotBlocks, ...): emit padded CSR — csr[d*MAXDEG + slot] = (s, bits(w))
__global__ __launch_bounds__(256) void dots_and_emit(
    const float* __restrict__ h, const float* __restrict__ W,
    float* __restrict__ a, float* __restrict__ c, int N,
    const int* __restrict__ src, const int* __restrict__ dst,
    const float* __restrict__ wgt,
    int* __restrict__ cursor, int2* __restrict__ csr, int E, int dotBlocks)
{
    if ((int)blockIdx.x < dotBlocks) {
        int gid  = blockIdx.x * 256 + threadIdx.x;
        int node = gid >> 6;
        int lane = threadIdx.x & 63;
        if (node >= N) return;
        const float2* h2 = (const float2*)(h + (size_t)node * 128);
        float2 v  = h2[lane];
        float2 wd = ((const float2*)W)[lane];
        float2 ws = ((const float2*)(W + 128))[lane];
        float sd = v.x * wd.x + v.y * wd.y;
        float ss = v.x * ws.x + v.y * ws.y;
        #pragma unroll
        for (int off = 32; off; off >>= 1) {
            sd += __shfl_xor(sd, off, 64);
            ss += __shfl_xor(ss, off, 64);
        }
        if (lane == 0) { a[node] = sd; c[node] = ss; }
    } else {
        int e = (blockIdx.x - dotBlocks) * 256 + threadIdx.x;
        if (e >= E) return;
        int d = dst[e];
        int slot = atomicAdd(&cursor[d], 1);
        if (slot < MAXDEG)
            csr[(size_t)d * MAXDEG + slot] = make_int2(src[e], __float_as_int(wgt[e]));
    }
}

// One block per 1024-float row segment (same 147K-block shape as the proven fill).
// Stage this segment's edges into LDS, then each thread composes its float4
// (NEG with patched lanes) and does ONE store — no RMW, no store-store ordering.
__global__ __launch_bounds__(256) void fill_patch(
    float4* __restrict__ out4,
    const float* __restrict__ a, const float* __restrict__ c,
    const int* __restrict__ cursor, const int2* __restrict__ csr,
    const float* __restrict__ W, const float* __restrict__ b, int N)
{
    __shared__ int   pcol[256];
    __shared__ float pval[256];
    __shared__ int   pcnt;

    int seg        = blockIdx.x;
    int segsPerRow = N >> 10;                 // N / 1024
    int r          = seg / segsPerRow;        // magic-mul division
    int colBase    = (seg - r * segsPerRow) << 10;
    int tid        = threadIdx.x;

    if (tid == 0) pcnt = 0;
    __syncthreads();

    int   cnt  = min(cursor[r], MAXDEG);
    float w256 = W[256];
    float bb   = b[0];
    float ar   = a[r];

    for (int i = tid; i < cnt; i += 256) {
        int2 eo  = csr[(size_t)r * MAXDEG + i];
        int  rel = eo.x - colBase;
        if ((unsigned)rel < SEGF) {
            int k = atomicAdd(&pcnt, 1);
            if (k < 256) {
                pcol[k] = rel;
                pval[k] = fmaf(__int_as_float(eo.y), w256, ar + c[eo.x] + bb);
            }
        }
    }
    __syncthreads();

    float4 v = make_float4(NEG_VAL, NEG_VAL, NEG_VAL, NEG_VAL);
    int m = min(pcnt, 256);
    for (int k = 0; k < m; ++k) {
        int rel = pcol[k];                    // LDS broadcast (uniform addr)
        if ((rel >> 2) == tid) ((float*)&v)[rel & 3] = pval[k];
    }
    out4[(size_t)seg * (SEGF / 4) + tid] = v;
}

extern "C" void kernel_launch(void* const* d_in, const int* in_sizes, int n_in,
                              void* d_out, int out_size, void* d_ws, size_t ws_size,
                              hipStream_t stream) {
    const float* h       = (const float*)d_in[0];  // [N, 128]
    const int*   sources = (const int*)d_in[1];    // [E]
    const int*   dests   = (const int*)d_in[2];    // [E]
    const float* weights = (const float*)d_in[3];  // [E]
    const float* W       = (const float*)d_in[4];  // [257]
    const float* b       = (const float*)d_in[5];  // [1]
    float* out = (float*)d_out;                    // [N, N]

    const int N = in_sizes[0] / 128;               // 12288
    const int E = in_sizes[1];                     // 393216

    // ws layout: a[N] f32 | c[N] f32 | cursor[N] i32 | csr[N*MAXDEG] int2
    float* a      = (float*)d_ws;
    float* c      = a + N;
    int*   cursor = (int*)(c + N);
    int2*  csr    = (int2*)(cursor + N);
    size_t wsNeed = (size_t)N * 12 + (size_t)N * MAXDEG * 8;

    if ((N % 1024) == 0 && ws_size >= wsNeed) {
        // CSR fused path: zero cursor -> dots+emit -> fill+patch
        zero_cursor<<<(N + 255) / 256, 256, 0, stream>>>(cursor, N);

        int dotBlocks  = N / 4;                    // wave per node, 4 per block
        int emitBlocks = (E + 255) / 256;
        dots_and_emit<<<dotBlocks + emitBlocks, 256, 0, stream>>>(
            h, W, a, c, N, sources, dests, weights, cursor, csr, E, dotBlocks);

        int nseg = (N >> 10) * N;                  // 147456 blocks (proven shape)
        fill_patch<<<nseg, 256, 0, stream>>>(
            (float4*)out, a, c, cursor, csr, W, b, N);
    } else {
        // fallback: proven R3 path
        long long n4 = (long long)out_size / 4;
        int fillBlocks = (int)((n4 + 255) / 256);
        int dotBlocks  = (N + 3) / 4;
        fill_and_dots<<<fillBlocks + dotBlocks, 256, 0, stream>>>(
            (float4*)out, n4, fillBlocks, h, W, a, c, N);
        int blocks = (E + 255) / 256;
        edge_scatter<<<blocks, 256, 0, stream>>>(sources, dests, weights, a, c, W, b,
                                                 out, E, N);
    }
}

// Round 5
// 666.008 us; speedup vs baseline: 1.0721x; 1.0721x over previous
//
#include <hip/hip_runtime.h>

#define NEG_VAL -1000000000.0f
#define MAXDEG  128      // padded CSR row capacity (deg ~ Poisson(32), max ~57 over 12288 rows)
#define OVFCAP  4096     // overflow list capacity (never hit in practice)
#define SEGF    1024     // floats per fill segment (one 256-thread block each)

// ---------------- fallback path (proven R3 kernels) ----------------

__global__ __launch_bounds__(256) void fill_and_dots(
    float4* __restrict__ out4, long long n4, int fillBlocks,
    const float* __restrict__ h, const float* __restrict__ W,
    float* __restrict__ a, float* __restrict__ c, int N)
{
    if ((int)blockIdx.x < fillBlocks) {
        long long i = (long long)blockIdx.x * 256 + threadIdx.x;
        if (i < n4) out4[i] = make_float4(NEG_VAL, NEG_VAL, NEG_VAL, NEG_VAL);
    } else {
        int gid  = (blockIdx.x - fillBlocks) * 256 + threadIdx.x;
        int node = gid >> 6;
        int lane = threadIdx.x & 63;
        if (node >= N) return;
        const float2* h2 = (const float2*)(h + (size_t)node * 128);
        float2 v  = h2[lane];
        float2 wd = ((const float2*)W)[lane];
        float2 ws = ((const float2*)(W + 128))[lane];
        float sd = v.x * wd.x + v.y * wd.y;
        float ss = v.x * ws.x + v.y * ws.y;
        #pragma unroll
        for (int off = 32; off; off >>= 1) {
            sd += __shfl_xor(sd, off, 64);
            ss += __shfl_xor(ss, off, 64);
        }
        if (lane == 0) { a[node] = sd; c[node] = ss; }
    }
}

__global__ __launch_bounds__(256) void edge_scatter(
    const int* __restrict__ src, const int* __restrict__ dst,
    const float* __restrict__ wgt, const float* __restrict__ a,
    const float* __restrict__ c, const float* __restrict__ W,
    const float* __restrict__ b, float* __restrict__ out, int E, int N)
{
    int e = blockIdx.x * blockDim.x + threadIdx.x;
    if (e >= E) return;
    int s = src[e];
    int d = dst[e];
    out[(size_t)d * N + s] = fmaf(wgt[e], W[256], a[d] + c[s] + b[0]);
}

// ---------------- CSR fused path ----------------

__global__ __launch_bounds__(256) void zero_meta(int* __restrict__ cursor, int N,
                                                 int* __restrict__ ovf_cnt) {
    int i = blockIdx.x * 256 + threadIdx.x;
    if (i < N) cursor[i] = 0;
    if (i == 0) *ovf_cnt = 0;
}

// blocks [0, dotBlocks): per-node dots (one wave per node)
// blocks [dotBlocks, ..): emit padded CSR: csr[d*MAXDEG+slot] = (s, bits(w));
//                         overflow (slot >= MAXDEG) goes to a global list.
__global__ __launch_bounds__(256) void dots_and_emit(
    const float* __restrict__ h, const float* __restrict__ W,
    float* __restrict__ a, float* __restrict__ c, int N,
    const int* __restrict__ src, const int* __restrict__ dst,
    const float* __restrict__ wgt,
    int* __restrict__ cursor, int2* __restrict__ csr,
    int4* __restrict__ ovf, int* __restrict__ ovf_cnt,
    int E, int dotBlocks)
{
    if ((int)blockIdx.x < dotBlocks) {
        int gid  = blockIdx.x * 256 + threadIdx.x;
        int node = gid >> 6;
        int lane = threadIdx.x & 63;
        if (node >= N) return;
        const float2* h2 = (const float2*)(h + (size_t)node * 128);
        float2 v  = h2[lane];
        float2 wd = ((const float2*)W)[lane];
        float2 ws = ((const float2*)(W + 128))[lane];
        float sd = v.x * wd.x + v.y * wd.y;
        float ss = v.x * ws.x + v.y * ws.y;
        #pragma unroll
        for (int off = 32; off; off >>= 1) {
            sd += __shfl_xor(sd, off, 64);
            ss += __shfl_xor(ss, off, 64);
        }
        if (lane == 0) { a[node] = sd; c[node] = ss; }
    } else {
        int e = (blockIdx.x - dotBlocks) * 256 + threadIdx.x;
        if (e >= E) return;
        int d = dst[e];
        int s = src[e];
        int wbits = __float_as_int(wgt[e]);
        int slot = atomicAdd(&cursor[d], 1);
        if (slot < MAXDEG) {
            csr[(size_t)d * MAXDEG + slot] = make_int2(s, wbits);
        } else {
            int k = atomicAdd(ovf_cnt, 1);
            if (k < OVFCAP) ovf[k] = make_int4(d, s, wbits, 0);
        }
    }
}

// One block per 1024-float row segment (147456 blocks — the proven fill shape).
// The NEG float4 store issues FIRST (dependency-free, keeps the write stream at
// full rate). Patch loads overlap it; __syncthreads() drains vmcnt so the 4B
// patch stores land after the fill stores in this block's (single-XCD) L2.
// All writes to any 64B line come from ONE block -> no cross-XCD hazard.
__global__ __launch_bounds__(256) void fill_patch(
    float* __restrict__ out,
    const float* __restrict__ a, const float* __restrict__ c,
    const int* __restrict__ cursor, const int2* __restrict__ csr,
    const int4* __restrict__ ovf, const int* __restrict__ ovf_cnt,
    const float* __restrict__ W, const float* __restrict__ b,
    int segsPerRow)
{
    int seg = blockIdx.x;
    int tid = threadIdx.x;
    int r   = seg / segsPerRow;
    int colBase = (seg - r * segsPerRow) << 10;

    // 1) fill store, no dependencies
    float4* out4 = (float4*)out + (size_t)seg * (SEGF / 4);
    out4[tid] = make_float4(NEG_VAL, NEG_VAL, NEG_VAL, NEG_VAL);

    // 2) patch loads (overlap the store)
    int cnt = cursor[r];
    if (cnt > MAXDEG) cnt = MAXDEG;
    int2  eo;
    float ar = 0.f, w256 = 0.f, bb = 0.f, cs = 0.f;
    int   rel = -1;
    bool  mine = (tid < cnt);
    if (mine) {
        eo  = csr[(size_t)r * MAXDEG + tid];
        rel = eo.x - colBase;
        mine = ((unsigned)rel < SEGF);
        if (mine) {
            ar = a[r]; w256 = W[256]; bb = b[0]; cs = c[eo.x];
        }
    }
    int no = *ovf_cnt;

    __syncthreads();   // drains vmcnt: fill stores complete before patches issue

    // 3) patch stores (4B, L2-hit on just-written lines)
    if (mine) {
        out[(size_t)seg * SEGF + rel] = fmaf(__int_as_float(eo.y), w256, ar + cs + bb);
    }
    // 4) overflow (empty in practice; one broadcast scalar load when zero)
    if (no > 0) {
        if (no > OVFCAP) no = OVFCAP;
        for (int k = tid; k < no; k += 256) {
            int4 o = ovf[k];
            if (o.x == r) {
                int rr = o.y - colBase;
                if ((unsigned)rr < SEGF) {
                    out[(size_t)seg * SEGF + rr] =
                        fmaf(__int_as_float(o.z), W[256], a[r] + c[o.y] + b[0]);
                }
            }
        }
    }
}

extern "C" void kernel_launch(void* const* d_in, const int* in_sizes, int n_in,
                              void* d_out, int out_size, void* d_ws, size_t ws_size,
                              hipStream_t stream) {
    const float* h       = (const float*)d_in[0];  // [N, 128]
    const int*   sources = (const int*)d_in[1];    // [E]
    const int*   dests   = (const int*)d_in[2];    // [E]
    const float* weights = (const float*)d_in[3];  // [E]
    const float* W       = (const float*)d_in[4];  // [257]
    const float* b       = (const float*)d_in[5];  // [1]
    float* out = (float*)d_out;                    // [N, N]

    const int N = in_sizes[0] / 128;               // 12288
    const int E = in_sizes[1];                     // 393216

    // ws layout: a[N] | c[N] | cursor[N] | ovf[OVFCAP] int4 | ovf_cnt | pad | csr
    float* a       = (float*)d_ws;
    float* c       = a + N;
    int*   cursor  = (int*)(c + N);
    int4*  ovf     = (int4*)(cursor + N);               // offset N*12 bytes (16B aligned)
    int*   ovf_cnt = (int*)(ovf + OVFCAP);
    int2*  csr     = (int2*)(ovf_cnt + 4);              // keep 8B alignment
    size_t wsNeed  = (size_t)N * 12 + (size_t)OVFCAP * 16 + 16 + (size_t)N * MAXDEG * 8;

    if ((N % SEGF) == 0 && ws_size >= wsNeed) {
        zero_meta<<<(N + 255) / 256, 256, 0, stream>>>(cursor, N, ovf_cnt);

        int dotBlocks  = N / 4;                    // one wave per node, 4 per block
        int emitBlocks = (E + 255) / 256;
        dots_and_emit<<<dotBlocks + emitBlocks, 256, 0, stream>>>(
            h, W, a, c, N, sources, dests, weights, cursor, csr, ovf, ovf_cnt,
            E, dotBlocks);

        int segsPerRow = N / SEGF;                 // 12
        int nseg       = segsPerRow * N;           // 147456 blocks (proven shape)
        fill_patch<<<nseg, 256, 0, stream>>>(
            out, a, c, cursor, csr, ovf, ovf_cnt, W, b, segsPerRow);
    } else {
        // fallback: proven R3 path
        long long n4 = (long long)out_size / 4;
        int fillBlocks = (int)((n4 + 255) / 256);
        int dotBlocks  = (N + 3) / 4;
        fill_and_dots<<<fillBlocks + dotBlocks, 256, 0, stream>>>(
            (float4*)out, n4, fillBlocks, h, W, a, c, N);
        int blocks = (E + 255) / 256;
        edge_scatter<<<blocks, 256, 0, stream>>>(sources, dests, weights, a, c, W, b,
                                                 out, E, N);
    }
}

// Round 6
// 650.039 us; speedup vs baseline: 1.0985x; 1.0246x over previous
//
#include <hip/hip_runtime.h>

#define NEG_VAL -1000000000.0f
#define FILL_UNROLL 4   // float4 stores per thread, block-strided (each store coalesced)

// Fused kernel, fill-first ordering (R3 structure, unrolled fill):
//   blocks [0, fillBlocks)                   : NEG fill. Each thread issues
//     FILL_UNROLL block-strided float4 stores — every store instruction covers
//     256 lanes x 16B = 4KB contiguous; a block covers 16KB. 4 independent
//     stores per thread -> deeper store pipeline, 4x fewer workgroups.
//   blocks [fillBlocks, fillBlocks+dotBlocks): per-node partial dots, one
//     64-lane wave per node (trailing so the write stream starts immediately;
//     6.3 MB of reads hide under the 604 MB write stream).
//       a[n] = dot(h[n], W[0:128])   (used when n is a dest)
//       c[n] = dot(h[n], W[128:256]) (used when n is a source)
__global__ __launch_bounds__(256) void fill_and_dots(
    float4* __restrict__ out4,
    long long n4,
    int fillBlocks,
    const float* __restrict__ h,
    const float* __restrict__ W,
    float* __restrict__ a,
    float* __restrict__ c,
    int N)
{
    if ((int)blockIdx.x < fillBlocks) {
        const float4 v = make_float4(NEG_VAL, NEG_VAL, NEG_VAL, NEG_VAL);
        long long base = (long long)blockIdx.x * (256 * FILL_UNROLL) + threadIdx.x;
        #pragma unroll
        for (int k = 0; k < FILL_UNROLL; ++k) {
            long long i = base + (long long)k * 256;
            if (i < n4) out4[i] = v;
        }
    } else {
        int gid  = (blockIdx.x - fillBlocks) * 256 + threadIdx.x;
        int node = gid >> 6;
        int lane = threadIdx.x & 63;
        if (node >= N) return;

        const float2* h2 = (const float2*)(h + (size_t)node * 128);
        float2 v  = h2[lane];
        float2 wd = ((const float2*)W)[lane];           // W[2*lane], W[2*lane+1]
        float2 ws = ((const float2*)(W + 128))[lane];   // W[128+2*lane], ...

        float sd = v.x * wd.x + v.y * wd.y;
        float ss = v.x * ws.x + v.y * ws.y;

        #pragma unroll
        for (int off = 32; off; off >>= 1) {
            sd += __shfl_xor(sd, off, 64);
            ss += __shfl_xor(ss, off, 64);
        }
        if (lane == 0) { a[node] = sd; c[node] = ss; }
    }
}

// Per-edge scatter of the linear-layer output.
// val = a[d] + c[s] + wgt*W[256] + b ; out[d*N + s] = val
__global__ __launch_bounds__(256) void edge_scatter(
    const int* __restrict__ src,
    const int* __restrict__ dst,
    const float* __restrict__ wgt,
    const float* __restrict__ a,
    const float* __restrict__ c,
    const float* __restrict__ W,
    const float* __restrict__ b,
    float* __restrict__ out,
    int E, int N)
{
    int e = blockIdx.x * blockDim.x + threadIdx.x;
    if (e >= E) return;
    int s = src[e];
    int d = dst[e];
    out[(size_t)d * N + s] = fmaf(wgt[e], W[256], a[d] + c[s] + b[0]);
}

extern "C" void kernel_launch(void* const* d_in, const int* in_sizes, int n_in,
                              void* d_out, int out_size, void* d_ws, size_t ws_size,
                              hipStream_t stream) {
    const float* h       = (const float*)d_in[0];  // [N, 128]
    const int*   sources = (const int*)d_in[1];    // [E]
    const int*   dests   = (const int*)d_in[2];    // [E]
    const float* weights = (const float*)d_in[3];  // [E]
    const float* W       = (const float*)d_in[4];  // [257]
    const float* b       = (const float*)d_in[5];  // [1]
    float* out = (float*)d_out;                    // [N, N]

    const int N = in_sizes[0] / 128;               // 12288
    const int E = in_sizes[1];                     // 393216

    float* a = (float*)d_ws;                       // [N]
    float* c = a + N;                              // [N]

    // 1) fused: NEG fill (first, unrolled) + node dots (trailing blocks)
    {
        long long n4 = (long long)out_size / 4;            // N*N/4 float4s
        long long per = 256LL * FILL_UNROLL;               // float4s per block
        int fillBlocks = (int)((n4 + per - 1) / per);      // 36864 for N=12288
        int dotBlocks  = (N + 3) / 4;                      // 4 waves (nodes) per block
        fill_and_dots<<<fillBlocks + dotBlocks, 256, 0, stream>>>(
            (float4*)out, n4, fillBlocks, h, W, a, c, N);
    }

    // 2) scatter edge values (depends on fill + dots; same stream serializes)
    {
        int blocks = (E + 255) / 256;
        edge_scatter<<<blocks, 256, 0, stream>>>(sources, dests, weights, a, c, W, b,
                                                 out, E, N);
    }
}

// Round 7
// 626.202 us; speedup vs baseline: 1.1403x; 1.0381x over previous
//
#include <hip/hip_runtime.h>

#define NEG_VAL -1000000000.0f

// Fused kernel, fill-first ordering — BEST MEASURED (R3: 630.3 us).
// Six structural variants all regressed or were neutral:
//   NT stores (-44us), grid-stride fill (-44), CSR fill-patch heavy (-84),
//   CSR fill-patch slim (-36), 4x store unroll (-20), dot-launch fusion (0).
// The timed loop is dominated by the harness's 2.416 GB poison fill (~397us
// @ 6.1 TB/s) + our mandatory 604 MB output fill (~100us, same write ceiling).
//
//   blocks [0, fillBlocks)                 : NEG fill, ONE plain float4 store
//                                            per thread (~6 TB/s).
//   blocks [fillBlocks, fillBlocks+dotBlocks): per-node partial dots, one
//                                            64-lane wave per node; reads hide
//                                            under the write stream.
//       a[n] = dot(h[n], W[0:128])   (used when n is a dest)
//       c[n] = dot(h[n], W[128:256]) (used when n is a source)
__global__ __launch_bounds__(256) void fill_and_dots(
    float4* __restrict__ out4,
    long long n4,
    int fillBlocks,
    const float* __restrict__ h,
    const float* __restrict__ W,
    float* __restrict__ a,
    float* __restrict__ c,
    int N)
{
    if ((int)blockIdx.x < fillBlocks) {
        long long i = (long long)blockIdx.x * 256 + threadIdx.x;
        if (i < n4) {
            out4[i] = make_float4(NEG_VAL, NEG_VAL, NEG_VAL, NEG_VAL);
        }
    } else {
        int gid  = (blockIdx.x - fillBlocks) * 256 + threadIdx.x;
        int node = gid >> 6;
        int lane = threadIdx.x & 63;
        if (node >= N) return;

        const float2* h2 = (const float2*)(h + (size_t)node * 128);
        float2 v  = h2[lane];
        float2 wd = ((const float2*)W)[lane];           // W[2*lane], W[2*lane+1]
        float2 ws = ((const float2*)(W + 128))[lane];   // W[128+2*lane], ...

        float sd = v.x * wd.x + v.y * wd.y;
        float ss = v.x * ws.x + v.y * ws.y;

        #pragma unroll
        for (int off = 32; off; off >>= 1) {
            sd += __shfl_xor(sd, off, 64);
            ss += __shfl_xor(ss, off, 64);
        }
        if (lane == 0) {
            a[node] = sd;
            c[node] = ss;
        }
    }
}

// Per-edge scatter of the linear-layer output.
// val = a[d] + c[s] + wgt*W[256] + b ; out[d*N + s] = val
__global__ __launch_bounds__(256) void edge_scatter(
    const int* __restrict__ src,
    const int* __restrict__ dst,
    const float* __restrict__ wgt,
    const float* __restrict__ a,
    const float* __restrict__ c,
    const float* __restrict__ W,
    const float* __restrict__ b,
    float* __restrict__ out,
    int E, int N)
{
    int e = blockIdx.x * blockDim.x + threadIdx.x;
    if (e >= E) return;
    int s = src[e];
    int d = dst[e];
    float val = fmaf(wgt[e], W[256], a[d] + c[s] + b[0]);
    out[(size_t)d * N + s] = val;
}

extern "C" void kernel_launch(void* const* d_in, const int* in_sizes, int n_in,
                              void* d_out, int out_size, void* d_ws, size_t ws_size,
                              hipStream_t stream) {
    const float* h       = (const float*)d_in[0];  // [N, 128]
    const int*   sources = (const int*)d_in[1];    // [E]
    const int*   dests   = (const int*)d_in[2];    // [E]
    const float* weights = (const float*)d_in[3];  // [E]
    const float* W       = (const float*)d_in[4];  // [257]
    const float* b       = (const float*)d_in[5];  // [1]
    float* out = (float*)d_out;                    // [N, N]

    const int N = in_sizes[0] / 128;               // 12288
    const int E = in_sizes[1];                     // 393216

    float* a = (float*)d_ws;                       // [N]
    float* c = a + N;                              // [N]

    // 1) fused: NEG fill (first) + node dots (trailing blocks)
    {
        long long n4 = (long long)out_size / 4;            // out_size = N*N elements
        int fillBlocks = (int)((n4 + 255) / 256);          // one float4 per thread
        int dotBlocks  = (N + 3) / 4;                      // 4 waves (nodes) per block
        fill_and_dots<<<fillBlocks + dotBlocks, 256, 0, stream>>>(
            (float4*)out, n4, fillBlocks, h, W, a, c, N);
    }

    // 2) scatter edge values (depends on fill + dots; same stream serializes)
    {
        int blocks = (E + 255) / 256;
        edge_scatter<<<blocks, 256, 0, stream>>>(sources, dests, weights, a, c, W, b,
                                                 out, E, N);
    }
}